// Round 13
// baseline (1789.250 us; speedup 1.0000x reference)
//
#include <hip/hip_runtime.h>
#include <hip/hip_bf16.h>
#include <stdint.h>

#define EPSV 1e-5f

typedef __attribute__((ext_vector_type(4)))  int    i32x4;
typedef __attribute__((ext_vector_type(16))) int    i32x16;
typedef __attribute__((ext_vector_type(4)))  float  f32x4;

#define MFMA8(a, b, c) __builtin_amdgcn_mfma_i32_32x32x32_i8((a), (b), (c), 0, 0, 0)

__device__ __forceinline__ float clampf(float v, float lo, float hi) {
    return fminf(fmaxf(v, lo), hi);
}

__device__ __forceinline__ void gload16(const void* g, void* l) {
    __builtin_amdgcn_global_load_lds(
        (const __attribute__((address_space(1))) void*)g,
        (__attribute__((address_space(3))) void*)l, 16, 0, 0);
}

// Blocked i8 operand layout: matrix [R rows][K cols] (R,K multiples of 128) stored
// as 128x128 tiles of 16 KiB: tile = [frag 0..15][lane 0..63][16B], frag = ks*4+rf.
// Fragment (ks,rf) covers rows rf*32..+31, k-bytes ks*32..+31; lane l holds
// row rf*32+(l&31), bytes ks*32+(l>>5)*16..+15.  (round-1/3 verified mapping)
__device__ __forceinline__ size_t blk_off(int r, int k, int KB) {
    size_t tile = (size_t)((r >> 7) * KB + (k >> 7));
    int frag = (((k >> 5) & 3) << 2) + ((r >> 5) & 3);
    int lane = (r & 31) | (((k >> 4) & 1) << 5);
    return (tile * 16 + (size_t)frag) * 1024 + (size_t)lane * 16;
}

// ---------------- reduction: sum |w| (double partials, fixed order) ----------
__global__ void k_abs_sum(const float* __restrict__ w, long n4, double* __restrict__ part) {
    const f32x4* w4 = (const f32x4*)w;
    double s = 0.0;
    long stride = (long)gridDim.x * blockDim.x;
    for (long i = (long)blockIdx.x * blockDim.x + threadIdx.x; i < n4; i += stride) {
        f32x4 v = w4[i];
        s += (double)fabsf(v.x) + (double)fabsf(v.y) + (double)fabsf(v.z) + (double)fabsf(v.w);
    }
    for (int m = 1; m < 64; m <<= 1) s += __shfl_xor(s, m, 64);
    __shared__ double ls[4];
    int lane = threadIdx.x & 63, wid = threadIdx.x >> 6;
    if (lane == 0) ls[wid] = s;
    __syncthreads();
    if (threadIdx.x == 0) part[blockIdx.x] = ls[0] + ls[1] + ls[2] + ls[3];
}

__global__ void k_finalize(const double* __restrict__ p1, const double* __restrict__ p2,
                           int np, float* __restrict__ scal, double inv1, double inv2) {
    __shared__ double ls[4];
    for (int which = 0; which < 2; ++which) {
        const double* p = which ? p2 : p1;
        double s = 0.0;
        for (int i = threadIdx.x; i < np; i += 256) s += p[i];
        for (int m = 1; m < 64; m <<= 1) s += __shfl_xor(s, m, 64);
        int lane = threadIdx.x & 63, wid = threadIdx.x >> 6;
        if (lane == 0) ls[wid] = s;
        __syncthreads();
        if (threadIdx.x == 0) {
            double t = ls[0] + ls[1] + ls[2] + ls[3];
            scal[which] = fmaxf((float)(t * (which ? inv2 : inv1)), EPSV);
        }
        __syncthreads();
    }
}

// ---------------- packing helpers -------------------------------------------
__device__ __forceinline__ int pack4_mul(f32x4 v, float sc, float lo, float hi) {
    int a = (int)clampf(rintf(v.x * sc), lo, hi);
    int b = (int)clampf(rintf(v.y * sc), lo, hi);
    int c = (int)clampf(rintf(v.z * sc), lo, hi);
    int d = (int)clampf(rintf(v.w * sc), lo, hi);
    return (a & 255) | ((b & 255) << 8) | ((c & 255) << 16) | ((d & 255) << 24);
}
__device__ __forceinline__ int pack4_div(f32x4 v, float ws) {
    int a = (int)clampf(rintf(v.x / ws), -1.f, 1.f);
    int b = (int)clampf(rintf(v.y / ws), -1.f, 1.f);
    int c = (int)clampf(rintf(v.z / ws), -1.f, 1.f);
    int d = (int)clampf(rintf(v.w / ws), -1.f, 1.f);
    return (a & 255) | ((b & 255) << 8) | ((c & 255) << 16) | ((d & 255) << 24);
}

// ---------------- W quantize: ternary, blocked output ------------------------
__global__ void k_quant_w(const float* __restrict__ w, char* __restrict__ wq,
                          const float* __restrict__ scal, int which,
                          int KB, int nchunk) {
    int r = blockIdx.x, t = threadIdx.x;
    float ws = scal[which];
    const float* wr_ = w + (size_t)r * (size_t)(KB * 128);
    for (int c = 0; c < nchunk; ++c) {
        int k = c * 4096 + t * 16;
        const float* p = wr_ + k;
        i32x4 q;
        q.x = pack4_div(*(const f32x4*)(p + 0), ws);
        q.y = pack4_div(*(const f32x4*)(p + 4), ws);
        q.z = pack4_div(*(const f32x4*)(p + 8), ws);
        q.w = pack4_div(*(const f32x4*)(p + 12), ws);
        *(i32x4*)(wq + blk_off(r, k, KB)) = q;
    }
}

// ---------------- x quantize: per-row int8, blocked output -------------------
__global__ void k_quant_x(const float* __restrict__ x, char* __restrict__ xq,
                          float* __restrict__ xs1) {
    const int KB = 32;  // K = 4096
    int r = blockIdx.x, t = threadIdx.x;
    const float* xr = x + (size_t)r * 4096;
    f32x4 v0 = *(const f32x4*)(xr + t * 16 + 0);
    f32x4 v1 = *(const f32x4*)(xr + t * 16 + 4);
    f32x4 v2 = *(const f32x4*)(xr + t * 16 + 8);
    f32x4 v3 = *(const f32x4*)(xr + t * 16 + 12);
    float m = 0.f;
#define MX(vv) m = fmaxf(m, fmaxf(fmaxf(fabsf(vv.x), fabsf(vv.y)), fmaxf(fabsf(vv.z), fabsf(vv.w))))
    MX(v0); MX(v1); MX(v2); MX(v3);
#undef MX
    for (int mask = 1; mask < 64; mask <<= 1) m = fmaxf(m, __shfl_xor(m, mask, 64));
    __shared__ float wm[4];
    int lane = t & 63, wid = t >> 6;
    if (lane == 0) wm[wid] = m;
    __syncthreads();
    float rm = fmaxf(fmaxf(wm[0], wm[1]), fmaxf(wm[2], wm[3]));
    float sc = 127.f / fmaxf(rm, EPSV);
    if (t == 0) xs1[r] = sc;
    i32x4 q;
    q.x = pack4_mul(v0, sc, -128.f, 127.f);
    q.y = pack4_mul(v1, sc, -128.f, 127.f);
    q.z = pack4_mul(v2, sc, -128.f, 127.f);
    q.w = pack4_mul(v3, sc, -128.f, 127.f);
    *(i32x4*)(xq + blk_off(r, t * 16, KB)) = q;
}

// ---------------- per-row layer-2 scales -------------------------------------
__global__ void k_rowscale2(const int* __restrict__ rowmax1, const float* __restrict__ xs1,
                            const float* __restrict__ scal, float* __restrict__ xs2,
                            float* __restrict__ os2, float* __restrict__ g1s,
                            int rowOff, int R) {
    int i = blockIdx.x * 256 + threadIdx.x;
    if (i >= R) return;
    int r = rowOff + i;
    float g1 = scal[0] / xs1[r];
    float rmh = g1 * (float)rowmax1[r];
    float s2 = 127.f / fmaxf(rmh, EPSV);
    xs2[r] = s2;
    os2[r] = scal[1] / s2;
    g1s[r] = g1;
}

// ---------------- h requantize: C1 int32 -> int8 blocked ----------------------
__global__ void k_quant_h(const int* __restrict__ c1, char* __restrict__ xq2,
                          const float* __restrict__ xs2, const float* __restrict__ g1s,
                          int rowOff) {
    const int KB = 128;  // K = 16384
    int rl = blockIdx.x, t = threadIdx.x;
    int rg = rowOff + rl;
    float g1 = g1s[rg], s2 = xs2[rg];
    const int* cr = c1 + (size_t)rl * 16384;
#pragma unroll
    for (int c = 0; c < 4; ++c) {
        int k = c * 4096 + t * 16;
        const int* p = cr + k;
        i32x4 w0 = *(const i32x4*)(p + 0);
        i32x4 w1 = *(const i32x4*)(p + 4);
        i32x4 w2 = *(const i32x4*)(p + 8);
        i32x4 w3 = *(const i32x4*)(p + 12);
        i32x4 q;
#define QH(cc) ((int)clampf(rintf(fmaxf((float)(cc), 0.f) * g1 * s2), -128.f, 127.f) & 255)
        q.x = QH(w0.x) | (QH(w0.y) << 8) | (QH(w0.z) << 16) | (QH(w0.w) << 24);
        q.y = QH(w1.x) | (QH(w1.y) << 8) | (QH(w1.z) << 16) | (QH(w1.w) << 24);
        q.z = QH(w2.x) | (QH(w2.y) << 8) | (QH(w2.z) << 16) | (QH(w2.w) << 24);
        q.w = QH(w3.x) | (QH(w3.y) << 8) | (QH(w3.z) << 16) | (QH(w3.w) << 24);
#undef QH
        *(i32x4*)(xq2 + blk_off(rl, k, KB)) = q;
    }
}

// ---------------- int8 GEMM: 256x128 tile, 4 waves, 64x128/wave, 3-slot ring --
// Verified R10 structure (best measured: MfmaUtil 42%, 602 us/GEMM):
// 3-slot LDS ring (3x24KB), depth-2 prefetch, one counted vmcnt + one raw
// s_barrier per 64B K-step (never vmcnt(0) until tail), 2 blocks/CU.
template<int EPI>
__launch_bounds__(256, 2)
__global__ void k_gemm_i8(const char* __restrict__ A, const char* __restrict__ B,
                          int KBt, int NBX,
                          int* __restrict__ C, int* __restrict__ rowmax,
                          float* __restrict__ Out, const float* __restrict__ os2,
                          int rowOff, int N) {
    __shared__ char smem[73728];
    const int tid = threadIdx.x;
    const int lane = tid & 63;
    const int wv = tid >> 6;       // 0..3: rows wv*64..wv*64+63 of the 256-row tile

    // bijective XCD-aware remap (nwg multiple of 8)
    const int nwg = (int)gridDim.x;
    const int cpx = nwg >> 3;
    const int bid = (int)blockIdx.x;
    const int wg = (bid & 7) * cpx + (bid >> 3);
    const int bx = wg % NBX, by = wg / NBX;

    // A: two 128-row blocked tile streams (rows by*256..+255); B: one
    const char* a0s = A + (size_t)(by * 2 + 0) * KBt * 16384 + tid * 16;
    const char* a1s = A + (size_t)(by * 2 + 1) * KBt * 16384 + tid * 16;
    const char* bs  = B + (size_t)bx * KBt * 16384 + tid * 16;

    // within-slot bases: A [0,16K) = [half][ks][rf]*1KB, B [16K,24K) = [ks][n]*1KB
    const int aoff = (wv >> 1) * 8192 + (wv & 1) * 2048 + lane * 16;
    const int boff = 16384 + lane * 16;

    i32x16 acc[2][4] = {};

    auto stage = [&](int s, int slot) {
        const size_t soff = ((size_t)(s >> 1) << 14) + (size_t)((s & 1) << 13);
        char* d = smem + slot + tid * 16;
        gload16(a0s + soff,        d);
        gload16(a0s + soff + 4096, d + 4096);
        gload16(a1s + soff,        d + 8192);
        gload16(a1s + soff + 4096, d + 12288);
        gload16(bs  + soff,        d + 16384);
        gload16(bs  + soff + 4096, d + 20480);
    };

    const int NS = KBt * 2;   // 64B K-steps (>= 4)
    int s0 = 0, s1 = 24576, s2 = 49152;   // ring slots

    stage(0, s0);
    stage(1, s1);
    asm volatile("s_waitcnt vmcnt(6)" ::: "memory");
    __builtin_amdgcn_s_barrier();

    for (int j = 0; j < NS; ++j) {
        if (j + 2 < NS) stage(j + 2, s2);
        {
            const char* ab = smem + s0 + aoff;
            const char* bb = smem + s0 + boff;
#pragma unroll
            for (int ks = 0; ks < 2; ++ks) {
                i32x4 a0 = *(const i32x4*)(ab + ks * 4096);
                i32x4 a1 = *(const i32x4*)(ab + ks * 4096 + 1024);
                i32x4 b0 = *(const i32x4*)(bb + ks * 4096);
                i32x4 b1 = *(const i32x4*)(bb + ks * 4096 + 1024);
                i32x4 b2 = *(const i32x4*)(bb + ks * 4096 + 2048);
                i32x4 b3 = *(const i32x4*)(bb + ks * 4096 + 3072);
                acc[0][0] = MFMA8(a0, b0, acc[0][0]);
                acc[0][1] = MFMA8(a0, b1, acc[0][1]);
                acc[0][2] = MFMA8(a0, b2, acc[0][2]);
                acc[0][3] = MFMA8(a0, b3, acc[0][3]);
                acc[1][0] = MFMA8(a1, b0, acc[1][0]);
                acc[1][1] = MFMA8(a1, b1, acc[1][1]);
                acc[1][2] = MFMA8(a1, b2, acc[1][2]);
                acc[1][3] = MFMA8(a1, b3, acc[1][3]);
            }
        }
        if (j + 1 < NS) {
            if (j + 2 < NS) { asm volatile("s_waitcnt vmcnt(6)" ::: "memory"); }
            else            { asm volatile("s_waitcnt vmcnt(0)" ::: "memory"); }
            __builtin_amdgcn_s_barrier();
        }
        int t = s0; s0 = s1; s1 = s2; s2 = t;
    }

    // C/D layout: col = lane&31, row = (reg&3) + 8*(reg>>2) + 4*(lane>>5)
    if (EPI == 1) {
#pragma unroll
        for (int m = 0; m < 2; ++m) {
#pragma unroll
            for (int r = 0; r < 16; ++r) {
                int v = acc[m][0][r];
                int v1 = acc[m][1][r]; v = v > v1 ? v : v1;
                int v2 = acc[m][2][r]; v = v > v2 ? v : v2;
                int v3 = acc[m][3][r]; v = v > v3 ? v : v3;
#pragma unroll
                for (int mk = 1; mk <= 16; mk <<= 1) {
                    int o = __shfl_xor(v, mk, 64);
                    v = v > o ? v : o;
                }
                if ((lane & 31) == 0) {
                    int row = by * 256 + wv * 64 + m * 32 + (r & 3) + 8 * (r >> 2) + 4 * (lane >> 5);
                    atomicMax(&rowmax[rowOff + row], v);
                }
            }
        }
#pragma unroll
        for (int m = 0; m < 2; ++m)
#pragma unroll
            for (int r = 0; r < 16; ++r) {
                int row = by * 256 + wv * 64 + m * 32 + (r & 3) + 8 * (r >> 2) + 4 * (lane >> 5);
                size_t base = (size_t)row * N + bx * 128 + (lane & 31);
#pragma unroll
                for (int n = 0; n < 4; ++n) C[base + n * 32] = acc[m][n][r];
            }
    } else {
#pragma unroll
        for (int m = 0; m < 2; ++m)
#pragma unroll
            for (int r = 0; r < 16; ++r) {
                int row = by * 256 + wv * 64 + m * 32 + (r & 3) + 8 * (r >> 2) + 4 * (lane >> 5);
                float s = os2[rowOff + row];
                size_t base = (size_t)(rowOff + row) * N + bx * 128 + (lane & 31);
#pragma unroll
                for (int n = 0; n < 4; ++n) Out[base + n * 32] = (float)acc[m][n][r] * s;
            }
    }
}

// ---------------- host ---------------------------------------------------------
extern "C" void kernel_launch(void* const* d_in, const int* in_sizes, int n_in,
                              void* d_out, int out_size, void* d_ws, size_t ws_size,
                              hipStream_t stream) {
    const float* x  = (const float*)d_in[0];
    const float* W1 = (const float*)d_in[1];
    const float* W2 = (const float*)d_in[2];
    float* out = (float*)d_out;

    const int M = 8192, K1 = 4096, H = 16384, NOUT = 4096;
    const int NPART = 2048;

    uint8_t* ws = (uint8_t*)d_ws;
    size_t off = 0;
    auto alloc = [&](size_t bytes) -> void* {
        void* p = ws + off;
        off = (off + bytes + 255) & ~(size_t)255;
        return p;
    };
    char*   wq1  = (char*)alloc((size_t)H * K1);      // blocked, KB=32
    char*   wq2  = (char*)alloc((size_t)NOUT * H);    // blocked, KB=128
    char*   xq1  = (char*)alloc((size_t)M * K1);      // blocked, KB=32
    double* pd1  = (double*)alloc(NPART * 8);
    double* pd2  = (double*)alloc(NPART * 8);
    float*  scal = (float*)alloc(256);
    float*  xs1  = (float*)alloc(M * 4);
    float*  xs2  = (float*)alloc(M * 4);
    float*  os2  = (float*)alloc(M * 4);
    float*  g1s  = (float*)alloc(M * 4);
    int*    rm1  = (int*)alloc(M * 4);

    size_t remain = (ws_size > off) ? (ws_size - off) : 0;
    size_t perRow = (size_t)H * 4 + (size_t)H;   // C1 row + xq2 row
    long Rl = (long)(remain / perRow);
    int R = (int)((Rl / 256) * 256);
    if (R > 2048) R = 2048;      // cap: C1 chunk = 134 MB -> Infinity-Cache resident
    if (R < 256) R = 256;
    int*  C1  = (int*)alloc((size_t)R * H * 4);   // row-major int32, local rows
    char* xq2 = (char*)alloc((size_t)R * H);      // blocked (local rows), KB=128

    hipMemsetAsync(rm1, 0, M * 4, stream);
    k_abs_sum<<<NPART, 256, 0, stream>>>(W1, (long)H * K1 / 4, pd1);
    k_abs_sum<<<NPART, 256, 0, stream>>>(W2, (long)NOUT * H / 4, pd2);
    k_finalize<<<1, 256, 0, stream>>>(pd1, pd2, NPART, scal,
                                      1.0 / ((double)H * K1), 1.0 / ((double)NOUT * H));
    k_quant_w<<<H, 256, 0, stream>>>(W1, wq1, scal, 0, 32, 1);
    k_quant_w<<<NOUT, 256, 0, stream>>>(W2, wq2, scal, 1, 128, 4);
    k_quant_x<<<M, 256, 0, stream>>>(x, xq1, xs1);

    for (int rowOff = 0; rowOff < M; rowOff += R) {
        int Mc = (M - rowOff < R) ? (M - rowOff) : R;
        int nby = Mc / 256;
        // GEMM1: [Mc x 4096] x [16384 x 4096]^T -> C1 int32 + rowmax
        k_gemm_i8<1><<<dim3(128 * nby), 256, 0, stream>>>(
            xq1 + (size_t)rowOff * K1, wq1, 32, 128, C1, rm1, nullptr, nullptr, rowOff, H);
        k_rowscale2<<<(Mc + 255) / 256, 256, 0, stream>>>(rm1, xs1, scal, xs2, os2, g1s, rowOff, Mc);
        k_quant_h<<<Mc, 256, 0, stream>>>(C1, xq2, xs2, g1s, rowOff);
        // GEMM2: [Mc x 16384] x [4096 x 16384]^T -> out f32
        k_gemm_i8<2><<<dim3(32 * nby), 256, 0, stream>>>(
            xq2, wq2, 128, 32, nullptr, nullptr, out, os2, rowOff, NOUT);
    }
}

// Round 14
// 1786.538 us; speedup vs baseline: 1.0015x; 1.0015x over previous
//
#include <hip/hip_runtime.h>
#include <hip/hip_bf16.h>
#include <stdint.h>

#define EPSV 1e-5f

typedef __attribute__((ext_vector_type(4)))  int    i32x4;
typedef __attribute__((ext_vector_type(16))) int    i32x16;
typedef __attribute__((ext_vector_type(4)))  float  f32x4;

#define MFMA8(a, b, c) __builtin_amdgcn_mfma_i32_32x32x32_i8((a), (b), (c), 0, 0, 0)

__device__ __forceinline__ float clampf(float v, float lo, float hi) {
    return fminf(fmaxf(v, lo), hi);
}

__device__ __forceinline__ void gload16(const void* g, void* l) {
    __builtin_amdgcn_global_load_lds(
        (const __attribute__((address_space(1))) void*)g,
        (__attribute__((address_space(3))) void*)l, 16, 0, 0);
}

// Blocked i8 operand layout: matrix [R rows][K cols] (R,K multiples of 128) stored
// as 128x128 tiles of 16 KiB: tile = [frag 0..15][lane 0..63][16B], frag = ks*4+rf.
// Fragment (ks,rf) covers rows rf*32..+31, k-bytes ks*32..+31; lane l holds
// row rf*32+(l&31), bytes ks*32+(l>>5)*16..+15.  (round-1/3 verified mapping)
__device__ __forceinline__ size_t blk_off(int r, int k, int KB) {
    size_t tile = (size_t)((r >> 7) * KB + (k >> 7));
    int frag = (((k >> 5) & 3) << 2) + ((r >> 5) & 3);
    int lane = (r & 31) | (((k >> 4) & 1) << 5);
    return (tile * 16 + (size_t)frag) * 1024 + (size_t)lane * 16;
}

// ---------------- reduction: sum |w| (double partials, fixed order) ----------
__global__ void k_abs_sum(const float* __restrict__ w, long n4, double* __restrict__ part) {
    const f32x4* w4 = (const f32x4*)w;
    double s = 0.0;
    long stride = (long)gridDim.x * blockDim.x;
    for (long i = (long)blockIdx.x * blockDim.x + threadIdx.x; i < n4; i += stride) {
        f32x4 v = w4[i];
        s += (double)fabsf(v.x) + (double)fabsf(v.y) + (double)fabsf(v.z) + (double)fabsf(v.w);
    }
    for (int m = 1; m < 64; m <<= 1) s += __shfl_xor(s, m, 64);
    __shared__ double ls[4];
    int lane = threadIdx.x & 63, wid = threadIdx.x >> 6;
    if (lane == 0) ls[wid] = s;
    __syncthreads();
    if (threadIdx.x == 0) part[blockIdx.x] = ls[0] + ls[1] + ls[2] + ls[3];
}

__global__ void k_finalize(const double* __restrict__ p1, const double* __restrict__ p2,
                           int np, float* __restrict__ scal, double inv1, double inv2) {
    __shared__ double ls[4];
    for (int which = 0; which < 2; ++which) {
        const double* p = which ? p2 : p1;
        double s = 0.0;
        for (int i = threadIdx.x; i < np; i += 256) s += p[i];
        for (int m = 1; m < 64; m <<= 1) s += __shfl_xor(s, m, 64);
        int lane = threadIdx.x & 63, wid = threadIdx.x >> 6;
        if (lane == 0) ls[wid] = s;
        __syncthreads();
        if (threadIdx.x == 0) {
            double t = ls[0] + ls[1] + ls[2] + ls[3];
            scal[which] = fmaxf((float)(t * (which ? inv2 : inv1)), EPSV);
        }
        __syncthreads();
    }
}

// ---------------- packing helpers -------------------------------------------
__device__ __forceinline__ int pack4_mul(f32x4 v, float sc, float lo, float hi) {
    int a = (int)clampf(rintf(v.x * sc), lo, hi);
    int b = (int)clampf(rintf(v.y * sc), lo, hi);
    int c = (int)clampf(rintf(v.z * sc), lo, hi);
    int d = (int)clampf(rintf(v.w * sc), lo, hi);
    return (a & 255) | ((b & 255) << 8) | ((c & 255) << 16) | ((d & 255) << 24);
}
__device__ __forceinline__ int pack4_div(f32x4 v, float ws) {
    int a = (int)clampf(rintf(v.x / ws), -1.f, 1.f);
    int b = (int)clampf(rintf(v.y / ws), -1.f, 1.f);
    int c = (int)clampf(rintf(v.z / ws), -1.f, 1.f);
    int d = (int)clampf(rintf(v.w / ws), -1.f, 1.f);
    return (a & 255) | ((b & 255) << 8) | ((c & 255) << 16) | ((d & 255) << 24);
}

// ---------------- W quantize: ternary, blocked output ------------------------
__global__ void k_quant_w(const float* __restrict__ w, char* __restrict__ wq,
                          const float* __restrict__ scal, int which,
                          int KB, int nchunk) {
    int r = blockIdx.x, t = threadIdx.x;
    float ws = scal[which];
    const float* wr_ = w + (size_t)r * (size_t)(KB * 128);
    for (int c = 0; c < nchunk; ++c) {
        int k = c * 4096 + t * 16;
        const float* p = wr_ + k;
        i32x4 q;
        q.x = pack4_div(*(const f32x4*)(p + 0), ws);
        q.y = pack4_div(*(const f32x4*)(p + 4), ws);
        q.z = pack4_div(*(const f32x4*)(p + 8), ws);
        q.w = pack4_div(*(const f32x4*)(p + 12), ws);
        *(i32x4*)(wq + blk_off(r, k, KB)) = q;
    }
}

// ---------------- x quantize: per-row int8, blocked output -------------------
__global__ void k_quant_x(const float* __restrict__ x, char* __restrict__ xq,
                          float* __restrict__ xs1) {
    const int KB = 32;  // K = 4096
    int r = blockIdx.x, t = threadIdx.x;
    const float* xr = x + (size_t)r * 4096;
    f32x4 v0 = *(const f32x4*)(xr + t * 16 + 0);
    f32x4 v1 = *(const f32x4*)(xr + t * 16 + 4);
    f32x4 v2 = *(const f32x4*)(xr + t * 16 + 8);
    f32x4 v3 = *(const f32x4*)(xr + t * 16 + 12);
    float m = 0.f;
#define MX(vv) m = fmaxf(m, fmaxf(fmaxf(fabsf(vv.x), fabsf(vv.y)), fmaxf(fabsf(vv.z), fabsf(vv.w))))
    MX(v0); MX(v1); MX(v2); MX(v3);
#undef MX
    for (int mask = 1; mask < 64; mask <<= 1) m = fmaxf(m, __shfl_xor(m, mask, 64));
    __shared__ float wm[4];
    int lane = t & 63, wid = t >> 6;
    if (lane == 0) wm[wid] = m;
    __syncthreads();
    float rm = fmaxf(fmaxf(wm[0], wm[1]), fmaxf(wm[2], wm[3]));
    float sc = 127.f / fmaxf(rm, EPSV);
    if (t == 0) xs1[r] = sc;
    i32x4 q;
    q.x = pack4_mul(v0, sc, -128.f, 127.f);
    q.y = pack4_mul(v1, sc, -128.f, 127.f);
    q.z = pack4_mul(v2, sc, -128.f, 127.f);
    q.w = pack4_mul(v3, sc, -128.f, 127.f);
    *(i32x4*)(xq + blk_off(r, t * 16, KB)) = q;
}

// ---------------- per-row layer-2 scales -------------------------------------
__global__ void k_rowscale2(const int* __restrict__ rowmax1, const float* __restrict__ xs1,
                            const float* __restrict__ scal, float* __restrict__ xs2,
                            float* __restrict__ os2, float* __restrict__ g1s,
                            int rowOff, int R) {
    int i = blockIdx.x * 256 + threadIdx.x;
    if (i >= R) return;
    int r = rowOff + i;
    float g1 = scal[0] / xs1[r];
    float rmh = g1 * (float)rowmax1[r];
    float s2 = 127.f / fmaxf(rmh, EPSV);
    xs2[r] = s2;
    os2[r] = scal[1] / s2;
    g1s[r] = g1;
}

// ---------------- h requantize: C1 int32 -> int8 blocked ----------------------
__global__ void k_quant_h(const int* __restrict__ c1, char* __restrict__ xq2,
                          const float* __restrict__ xs2, const float* __restrict__ g1s,
                          int rowOff) {
    const int KB = 128;  // K = 16384
    int rl = blockIdx.x, t = threadIdx.x;
    int rg = rowOff + rl;
    float g1 = g1s[rg], s2 = xs2[rg];
    const int* cr = c1 + (size_t)rl * 16384;
#pragma unroll
    for (int c = 0; c < 4; ++c) {
        int k = c * 4096 + t * 16;
        const int* p = cr + k;
        i32x4 w0 = *(const i32x4*)(p + 0);
        i32x4 w1 = *(const i32x4*)(p + 4);
        i32x4 w2 = *(const i32x4*)(p + 8);
        i32x4 w3 = *(const i32x4*)(p + 12);
        i32x4 q;
#define QH(cc) ((int)clampf(rintf(fmaxf((float)(cc), 0.f) * g1 * s2), -128.f, 127.f) & 255)
        q.x = QH(w0.x) | (QH(w0.y) << 8) | (QH(w0.z) << 16) | (QH(w0.w) << 24);
        q.y = QH(w1.x) | (QH(w1.y) << 8) | (QH(w1.z) << 16) | (QH(w1.w) << 24);
        q.z = QH(w2.x) | (QH(w2.y) << 8) | (QH(w2.z) << 16) | (QH(w2.w) << 24);
        q.w = QH(w3.x) | (QH(w3.y) << 8) | (QH(w3.z) << 16) | (QH(w3.w) << 24);
#undef QH
        *(i32x4*)(xq2 + blk_off(rl, k, KB)) = q;
    }
}

// ---------------- int8 GEMM: 256x256 tile, 8 waves (4Mx2N), 64x128/wave -------
// R10's verified ring schedule at 3x the arithmetic intensity: staged bytes
// per step-slot drop 96KB -> 32KB (the measured binding resource: both R12
// GEMMs ran at identical 602us = identical 12.6GB staging volume ~ 21TB/s
// L2-feed). 3-slot ring of 32KB (96KB LDS), depth-2 prefetch, one counted
// vmcnt (4 loads/stage -> vmcnt(4)) + one raw s_barrier per 64B K-step.
template<int EPI>
__launch_bounds__(512, 2)
__global__ void k_gemm_i8(const char* __restrict__ A, const char* __restrict__ B,
                          int KBt, int NBX,
                          int* __restrict__ C, int* __restrict__ rowmax,
                          float* __restrict__ Out, const float* __restrict__ os2,
                          int rowOff, int N) {
    __shared__ char smem[98304];
    const int tid = threadIdx.x;
    const int lane = tid & 63;
    const int wv = tid >> 6;       // 0..7
    const int wr = wv >> 1;        // 0..3: row quarter (64 rows)
    const int wc = wv & 1;         // 0..1: col half (128 cols)

    // bijective XCD-aware remap (nwg multiple of 8)
    const int nwg = (int)gridDim.x;
    const int cpx = nwg >> 3;
    const int bid = (int)blockIdx.x;
    const int wg = (bid & 7) * cpx + (bid >> 3);
    const int bx = wg % NBX, by = wg / NBX;

    // A: two 128-row blocked tile streams (rows by*256..+255); B: two 128-col
    const char* a0s = A + (size_t)(by * 2 + 0) * KBt * 16384 + tid * 16;
    const char* a1s = A + (size_t)(by * 2 + 1) * KBt * 16384 + tid * 16;
    const char* b0s = B + (size_t)(bx * 2 + 0) * KBt * 16384 + tid * 16;
    const char* b1s = B + (size_t)(bx * 2 + 1) * KBt * 16384 + tid * 16;

    // within-slot: A [0,16K) = [rowhalf 8K][ks 4K][rf 1K]; B [16K,32K) same by col
    const int aoff = (wr >> 1) * 8192 + (wr & 1) * 2048 + lane * 16;
    const int boff = 16384 + wc * 8192 + lane * 16;

    i32x16 acc[2][4] = {};

    auto stage = [&](int s, int slot) {
        const size_t soff = ((size_t)(s >> 1) << 14) + (size_t)((s & 1) << 13);
        char* d = smem + slot + tid * 16;
        gload16(a0s + soff, d);
        gload16(a1s + soff, d + 8192);
        gload16(b0s + soff, d + 16384);
        gload16(b1s + soff, d + 24576);
    };

    const int NS = KBt * 2;   // 64B K-steps (>= 4)
    int s0 = 0, s1 = 32768, s2 = 65536;   // ring slots (32 KB each)

    stage(0, s0);
    stage(1, s1);
    asm volatile("s_waitcnt vmcnt(4)" ::: "memory");
    __builtin_amdgcn_s_barrier();

    for (int j = 0; j < NS; ++j) {
        if (j + 2 < NS) stage(j + 2, s2);
        {
            const char* ab = smem + s0 + aoff;
            const char* bb = smem + s0 + boff;
#pragma unroll
            for (int ks = 0; ks < 2; ++ks) {
                i32x4 a0 = *(const i32x4*)(ab + ks * 4096);
                i32x4 a1 = *(const i32x4*)(ab + ks * 4096 + 1024);
                i32x4 b0 = *(const i32x4*)(bb + ks * 4096);
                i32x4 b1 = *(const i32x4*)(bb + ks * 4096 + 1024);
                i32x4 b2 = *(const i32x4*)(bb + ks * 4096 + 2048);
                i32x4 b3 = *(const i32x4*)(bb + ks * 4096 + 3072);
                acc[0][0] = MFMA8(a0, b0, acc[0][0]);
                acc[0][1] = MFMA8(a0, b1, acc[0][1]);
                acc[0][2] = MFMA8(a0, b2, acc[0][2]);
                acc[0][3] = MFMA8(a0, b3, acc[0][3]);
                acc[1][0] = MFMA8(a1, b0, acc[1][0]);
                acc[1][1] = MFMA8(a1, b1, acc[1][1]);
                acc[1][2] = MFMA8(a1, b2, acc[1][2]);
                acc[1][3] = MFMA8(a1, b3, acc[1][3]);
            }
        }
        if (j + 1 < NS) {
            if (j + 2 < NS) { asm volatile("s_waitcnt vmcnt(4)" ::: "memory"); }
            else            { asm volatile("s_waitcnt vmcnt(0)" ::: "memory"); }
            __builtin_amdgcn_s_barrier();
        }
        int t = s0; s0 = s1; s1 = s2; s2 = t;
    }

    // C/D layout: col = lane&31, row = (reg&3) + 8*(reg>>2) + 4*(lane>>5)
    if (EPI == 1) {
#pragma unroll
        for (int m = 0; m < 2; ++m) {
#pragma unroll
            for (int r = 0; r < 16; ++r) {
                int v = acc[m][0][r];
                int v1 = acc[m][1][r]; v = v > v1 ? v : v1;
                int v2 = acc[m][2][r]; v = v > v2 ? v : v2;
                int v3 = acc[m][3][r]; v = v > v3 ? v : v3;
#pragma unroll
                for (int mk = 1; mk <= 16; mk <<= 1) {
                    int o = __shfl_xor(v, mk, 64);
                    v = v > o ? v : o;
                }
                if ((lane & 31) == 0) {
                    int row = by * 256 + wr * 64 + m * 32 + (r & 3) + 8 * (r >> 2) + 4 * (lane >> 5);
                    atomicMax(&rowmax[rowOff + row], v);
                }
            }
        }
#pragma unroll
        for (int m = 0; m < 2; ++m)
#pragma unroll
            for (int r = 0; r < 16; ++r) {
                int row = by * 256 + wr * 64 + m * 32 + (r & 3) + 8 * (r >> 2) + 4 * (lane >> 5);
                size_t base = (size_t)row * N + bx * 256 + wc * 128 + (lane & 31);
#pragma unroll
                for (int n = 0; n < 4; ++n) C[base + n * 32] = acc[m][n][r];
            }
    } else {
#pragma unroll
        for (int m = 0; m < 2; ++m)
#pragma unroll
            for (int r = 0; r < 16; ++r) {
                int row = by * 256 + wr * 64 + m * 32 + (r & 3) + 8 * (r >> 2) + 4 * (lane >> 5);
                float s = os2[rowOff + row];
                size_t base = (size_t)(rowOff + row) * N + bx * 256 + wc * 128 + (lane & 31);
#pragma unroll
                for (int n = 0; n < 4; ++n) Out[base + n * 32] = (float)acc[m][n][r] * s;
            }
    }
}

// ---------------- host ---------------------------------------------------------
extern "C" void kernel_launch(void* const* d_in, const int* in_sizes, int n_in,
                              void* d_out, int out_size, void* d_ws, size_t ws_size,
                              hipStream_t stream) {
    const float* x  = (const float*)d_in[0];
    const float* W1 = (const float*)d_in[1];
    const float* W2 = (const float*)d_in[2];
    float* out = (float*)d_out;

    const int M = 8192, K1 = 4096, H = 16384, NOUT = 4096;
    const int NPART = 2048;

    uint8_t* ws = (uint8_t*)d_ws;
    size_t off = 0;
    auto alloc = [&](size_t bytes) -> void* {
        void* p = ws + off;
        off = (off + bytes + 255) & ~(size_t)255;
        return p;
    };
    char*   wq1  = (char*)alloc((size_t)H * K1);      // blocked, KB=32
    char*   wq2  = (char*)alloc((size_t)NOUT * H);    // blocked, KB=128
    char*   xq1  = (char*)alloc((size_t)M * K1);      // blocked, KB=32
    double* pd1  = (double*)alloc(NPART * 8);
    double* pd2  = (double*)alloc(NPART * 8);
    float*  scal = (float*)alloc(256);
    float*  xs1  = (float*)alloc(M * 4);
    float*  xs2  = (float*)alloc(M * 4);
    float*  os2  = (float*)alloc(M * 4);
    float*  g1s  = (float*)alloc(M * 4);
    int*    rm1  = (int*)alloc(M * 4);

    size_t remain = (ws_size > off) ? (ws_size - off) : 0;
    size_t perRow = (size_t)H * 4 + (size_t)H;   // C1 row + xq2 row
    long Rl = (long)(remain / perRow);
    int R = (int)((Rl / 256) * 256);
    if (R > M) R = M;
    if (R < 256) R = 256;
    int*  C1  = (int*)alloc((size_t)R * H * 4);   // row-major int32, local rows
    char* xq2 = (char*)alloc((size_t)R * H);      // blocked (local rows), KB=128

    hipMemsetAsync(rm1, 0, M * 4, stream);
    k_abs_sum<<<NPART, 256, 0, stream>>>(W1, (long)H * K1 / 4, pd1);
    k_abs_sum<<<NPART, 256, 0, stream>>>(W2, (long)NOUT * H / 4, pd2);
    k_finalize<<<1, 256, 0, stream>>>(pd1, pd2, NPART, scal,
                                      1.0 / ((double)H * K1), 1.0 / ((double)NOUT * H));
    k_quant_w<<<H, 256, 0, stream>>>(W1, wq1, scal, 0, 32, 1);
    k_quant_w<<<NOUT, 256, 0, stream>>>(W2, wq2, scal, 1, 128, 4);
    k_quant_x<<<M, 256, 0, stream>>>(x, xq1, xs1);

    for (int rowOff = 0; rowOff < M; rowOff += R) {
        int Mc = (M - rowOff < R) ? (M - rowOff) : R;
        int nby = Mc / 256;
        // GEMM1: [Mc x 4096] x [16384 x 4096]^T -> C1 int32 + rowmax
        k_gemm_i8<1><<<dim3(64 * nby), 512, 0, stream>>>(
            xq1 + (size_t)rowOff * K1, wq1, 32, 64, C1, rm1, nullptr, nullptr, rowOff, H);
        k_rowscale2<<<(Mc + 255) / 256, 256, 0, stream>>>(rm1, xs1, scal, xs2, os2, g1s, rowOff, Mc);
        k_quant_h<<<Mc, 256, 0, stream>>>(C1, xq2, xs2, g1s, rowOff);
        // GEMM2: [Mc x 16384] x [4096 x 16384]^T -> out f32
        k_gemm_i8<2><<<dim3(16 * nby), 512, 0, stream>>>(
            xq2, wq2, 128, 16, nullptr, nullptr, out, os2, rowOff, NOUT);
    }
}

// Round 15
// 1492.629 us; speedup vs baseline: 1.1987x; 1.1969x over previous
//
#include <hip/hip_runtime.h>
#include <hip/hip_bf16.h>
#include <stdint.h>

#define EPSV 1e-5f

typedef __attribute__((ext_vector_type(4)))  int    i32x4;
typedef __attribute__((ext_vector_type(16))) int    i32x16;
typedef __attribute__((ext_vector_type(4)))  float  f32x4;

#define MFMA8(a, b, c) __builtin_amdgcn_mfma_i32_32x32x32_i8((a), (b), (c), 0, 0, 0)

__device__ __forceinline__ float clampf(float v, float lo, float hi) {
    return fminf(fmaxf(v, lo), hi);
}

__device__ __forceinline__ void gload16(const void* g, void* l) {
    __builtin_amdgcn_global_load_lds(
        (const __attribute__((address_space(1))) void*)g,
        (__attribute__((address_space(3))) void*)l, 16, 0, 0);
}

// Blocked i8 operand layout: matrix [R rows][K cols] (R,K multiples of 128) stored
// as 128x128 tiles of 16 KiB: tile = [frag 0..15][lane 0..63][16B], frag = ks*4+rf.
// Fragment (ks,rf) covers rows rf*32..+31, k-bytes ks*32..+31; lane l holds
// row rf*32+(l&31), bytes ks*32+(l>>5)*16..+15.  (round-1/3 verified mapping)
__device__ __forceinline__ size_t blk_off(int r, int k, int KB) {
    size_t tile = (size_t)((r >> 7) * KB + (k >> 7));
    int frag = (((k >> 5) & 3) << 2) + ((r >> 5) & 3);
    int lane = (r & 31) | (((k >> 4) & 1) << 5);
    return (tile * 16 + (size_t)frag) * 1024 + (size_t)lane * 16;
}

// ---------------- reduction: sum |w| (double partials, fixed order) ----------
__global__ void k_abs_sum(const float* __restrict__ w, long n4, double* __restrict__ part) {
    const f32x4* w4 = (const f32x4*)w;
    double s = 0.0;
    long stride = (long)gridDim.x * blockDim.x;
    for (long i = (long)blockIdx.x * blockDim.x + threadIdx.x; i < n4; i += stride) {
        f32x4 v = w4[i];
        s += (double)fabsf(v.x) + (double)fabsf(v.y) + (double)fabsf(v.z) + (double)fabsf(v.w);
    }
    for (int m = 1; m < 64; m <<= 1) s += __shfl_xor(s, m, 64);
    __shared__ double ls[4];
    int lane = threadIdx.x & 63, wid = threadIdx.x >> 6;
    if (lane == 0) ls[wid] = s;
    __syncthreads();
    if (threadIdx.x == 0) part[blockIdx.x] = ls[0] + ls[1] + ls[2] + ls[3];
}

__global__ void k_finalize(const double* __restrict__ p1, const double* __restrict__ p2,
                           int np, float* __restrict__ scal, double inv1, double inv2) {
    __shared__ double ls[4];
    for (int which = 0; which < 2; ++which) {
        const double* p = which ? p2 : p1;
        double s = 0.0;
        for (int i = threadIdx.x; i < np; i += 256) s += p[i];
        for (int m = 1; m < 64; m <<= 1) s += __shfl_xor(s, m, 64);
        int lane = threadIdx.x & 63, wid = threadIdx.x >> 6;
        if (lane == 0) ls[wid] = s;
        __syncthreads();
        if (threadIdx.x == 0) {
            double t = ls[0] + ls[1] + ls[2] + ls[3];
            scal[which] = fmaxf((float)(t * (which ? inv2 : inv1)), EPSV);
        }
        __syncthreads();
    }
}

// ---------------- packing helpers -------------------------------------------
__device__ __forceinline__ int pack4_mul(f32x4 v, float sc, float lo, float hi) {
    int a = (int)clampf(rintf(v.x * sc), lo, hi);
    int b = (int)clampf(rintf(v.y * sc), lo, hi);
    int c = (int)clampf(rintf(v.z * sc), lo, hi);
    int d = (int)clampf(rintf(v.w * sc), lo, hi);
    return (a & 255) | ((b & 255) << 8) | ((c & 255) << 16) | ((d & 255) << 24);
}
__device__ __forceinline__ int pack4_div(f32x4 v, float ws) {
    int a = (int)clampf(rintf(v.x / ws), -1.f, 1.f);
    int b = (int)clampf(rintf(v.y / ws), -1.f, 1.f);
    int c = (int)clampf(rintf(v.z / ws), -1.f, 1.f);
    int d = (int)clampf(rintf(v.w / ws), -1.f, 1.f);
    return (a & 255) | ((b & 255) << 8) | ((c & 255) << 16) | ((d & 255) << 24);
}

// ---------------- W quantize: ternary, tile-blocked contiguous writes ---------
// One block per 128x128 tile (4 waves x 4 frags). Lane l produces the 16 bytes
// at fragment offset l*16 -> each wave stores a full contiguous 1KB fragment
// (same blk_off mapping: frag = ks*4+rf, lane = (r&31)|((k>>4)&1)<<5 = l).
__global__ void k_quant_w(const float* __restrict__ w, char* __restrict__ wq,
                          const float* __restrict__ scal, int which, int NBK) {
    const int tile = blockIdx.x;
    const int tr = tile / NBK, tk = tile % NBK;
    const int t = threadIdx.x;
    const int l = t & 63;
    const int f0 = (t >> 6) * 4;
    const float ws = scal[which];
    const int Kc = NBK * 128;
    char* dst = wq + (size_t)(tr * NBK + tk) * 16384;
#pragma unroll
    for (int i = 0; i < 4; ++i) {
        int frag = f0 + i;
        int ks = frag >> 2, rf = frag & 3;
        int row = tr * 128 + rf * 32 + (l & 31);
        int kk  = tk * 128 + ks * 32 + ((l >> 5) << 4);
        const float* p = w + (size_t)row * Kc + kk;
        i32x4 q;
        q.x = pack4_div(*(const f32x4*)(p + 0), ws);
        q.y = pack4_div(*(const f32x4*)(p + 4), ws);
        q.z = pack4_div(*(const f32x4*)(p + 8), ws);
        q.w = pack4_div(*(const f32x4*)(p + 12), ws);
        *(i32x4*)(dst + (size_t)frag * 1024 + l * 16) = q;
    }
}

// ---------------- x quantize: per-row int8, blocked output -------------------
__global__ void k_quant_x(const float* __restrict__ x, char* __restrict__ xq,
                          float* __restrict__ xs1) {
    const int KB = 32;  // K = 4096
    int r = blockIdx.x, t = threadIdx.x;
    const float* xr = x + (size_t)r * 4096;
    f32x4 v0 = *(const f32x4*)(xr + t * 16 + 0);
    f32x4 v1 = *(const f32x4*)(xr + t * 16 + 4);
    f32x4 v2 = *(const f32x4*)(xr + t * 16 + 8);
    f32x4 v3 = *(const f32x4*)(xr + t * 16 + 12);
    float m = 0.f;
#define MX(vv) m = fmaxf(m, fmaxf(fmaxf(fabsf(vv.x), fabsf(vv.y)), fmaxf(fabsf(vv.z), fabsf(vv.w))))
    MX(v0); MX(v1); MX(v2); MX(v3);
#undef MX
    for (int mask = 1; mask < 64; mask <<= 1) m = fmaxf(m, __shfl_xor(m, mask, 64));
    __shared__ float wm[4];
    int lane = t & 63, wid = t >> 6;
    if (lane == 0) wm[wid] = m;
    __syncthreads();
    float rm = fmaxf(fmaxf(wm[0], wm[1]), fmaxf(wm[2], wm[3]));
    float sc = 127.f / fmaxf(rm, EPSV);
    if (t == 0) xs1[r] = sc;
    i32x4 q;
    q.x = pack4_mul(v0, sc, -128.f, 127.f);
    q.y = pack4_mul(v1, sc, -128.f, 127.f);
    q.z = pack4_mul(v2, sc, -128.f, 127.f);
    q.w = pack4_mul(v3, sc, -128.f, 127.f);
    *(i32x4*)(xq + blk_off(r, t * 16, KB)) = q;
}

// ---------------- per-row layer-2 scales -------------------------------------
__global__ void k_rowscale2(const int* __restrict__ rowmax1, const float* __restrict__ xs1,
                            const float* __restrict__ scal, float* __restrict__ xs2,
                            float* __restrict__ os2, float* __restrict__ g1s,
                            int rowOff, int R) {
    int i = blockIdx.x * 256 + threadIdx.x;
    if (i >= R) return;
    int r = rowOff + i;
    float g1 = scal[0] / xs1[r];
    float rmh = g1 * (float)rowmax1[r];
    float s2 = 127.f / fmaxf(rmh, EPSV);
    xs2[r] = s2;
    os2[r] = scal[1] / s2;
    g1s[r] = g1;
}

// ---------------- h requantize: tile-blocked contiguous writes ----------------
// One block per 128x128 tile of [Mc x 16384]; wave writes contiguous 1KB frags.
__global__ void k_quant_h(const int* __restrict__ c1, char* __restrict__ xq2,
                          const float* __restrict__ xs2, const float* __restrict__ g1s,
                          int rowOff) {
    const int NBK = 128;   // 16384/128
    const int tile = blockIdx.x;
    const int tr = tile / NBK, tk = tile % NBK;
    const int t = threadIdx.x;
    const int l = t & 63;
    const int f0 = (t >> 6) * 4;
    char* dst = xq2 + (size_t)(tr * NBK + tk) * 16384;
#pragma unroll
    for (int i = 0; i < 4; ++i) {
        int frag = f0 + i;
        int ks = frag >> 2, rf = frag & 3;
        int rl = tr * 128 + rf * 32 + (l & 31);
        int kk = tk * 128 + ks * 32 + ((l >> 5) << 4);
        int rg = rowOff + rl;
        float g1 = g1s[rg], s2 = xs2[rg];
        const int* p = c1 + (size_t)rl * 16384 + kk;
        i32x4 w0 = *(const i32x4*)(p + 0);
        i32x4 w1 = *(const i32x4*)(p + 4);
        i32x4 w2 = *(const i32x4*)(p + 8);
        i32x4 w3 = *(const i32x4*)(p + 12);
        i32x4 q;
#define QH(cc) ((int)clampf(rintf(fmaxf((float)(cc), 0.f) * g1 * s2), -128.f, 127.f) & 255)
        q.x = QH(w0.x) | (QH(w0.y) << 8) | (QH(w0.z) << 16) | (QH(w0.w) << 24);
        q.y = QH(w1.x) | (QH(w1.y) << 8) | (QH(w1.z) << 16) | (QH(w1.w) << 24);
        q.z = QH(w2.x) | (QH(w2.y) << 8) | (QH(w2.z) << 16) | (QH(w2.w) << 24);
        q.w = QH(w3.x) | (QH(w3.y) << 8) | (QH(w3.z) << 16) | (QH(w3.w) << 24);
#undef QH
        *(i32x4*)(dst + (size_t)frag * 1024 + l * 16) = q;
    }
}

// ---------------- int8 GEMM: 256x128 tile, 4 waves, 64x128/wave, 3-slot ring --
// Verified R10/R12 structure (best measured: MfmaUtil 42%, 602 us/GEMM):
// 3-slot LDS ring (3x24KB), depth-2 prefetch, one counted vmcnt + one raw
// s_barrier per 64B K-step (never vmcnt(0) until tail), 2 blocks/CU = two
// independent barrier domains (the overlap mechanism; single-domain variants
// R4/R5/R8/R14 all regressed).
template<int EPI>
__launch_bounds__(256, 2)
__global__ void k_gemm_i8(const char* __restrict__ A, const char* __restrict__ B,
                          int KBt, int NBX,
                          int* __restrict__ C, int* __restrict__ rowmax,
                          float* __restrict__ Out, const float* __restrict__ os2,
                          int rowOff, int N) {
    __shared__ char smem[73728];
    const int tid = threadIdx.x;
    const int lane = tid & 63;
    const int wv = tid >> 6;       // 0..3: rows wv*64..wv*64+63 of the 256-row tile

    // bijective XCD-aware remap (nwg multiple of 8)
    const int nwg = (int)gridDim.x;
    const int cpx = nwg >> 3;
    const int bid = (int)blockIdx.x;
    const int wg = (bid & 7) * cpx + (bid >> 3);
    const int bx = wg % NBX, by = wg / NBX;

    // A: two 128-row blocked tile streams (rows by*256..+255); B: one
    const char* a0s = A + (size_t)(by * 2 + 0) * KBt * 16384 + tid * 16;
    const char* a1s = A + (size_t)(by * 2 + 1) * KBt * 16384 + tid * 16;
    const char* bs  = B + (size_t)bx * KBt * 16384 + tid * 16;

    // within-slot bases: A [0,16K) = [half][ks][rf]*1KB, B [16K,24K) = [ks][n]*1KB
    const int aoff = (wv >> 1) * 8192 + (wv & 1) * 2048 + lane * 16;
    const int boff = 16384 + lane * 16;

    i32x16 acc[2][4] = {};

    auto stage = [&](int s, int slot) {
        const size_t soff = ((size_t)(s >> 1) << 14) + (size_t)((s & 1) << 13);
        char* d = smem + slot + tid * 16;
        gload16(a0s + soff,        d);
        gload16(a0s + soff + 4096, d + 4096);
        gload16(a1s + soff,        d + 8192);
        gload16(a1s + soff + 4096, d + 12288);
        gload16(bs  + soff,        d + 16384);
        gload16(bs  + soff + 4096, d + 20480);
    };

    const int NS = KBt * 2;   // 64B K-steps (>= 4)
    int s0 = 0, s1 = 24576, s2 = 49152;   // ring slots

    stage(0, s0);
    stage(1, s1);
    asm volatile("s_waitcnt vmcnt(6)" ::: "memory");
    __builtin_amdgcn_s_barrier();

    for (int j = 0; j < NS; ++j) {
        if (j + 2 < NS) stage(j + 2, s2);
        {
            const char* ab = smem + s0 + aoff;
            const char* bb = smem + s0 + boff;
#pragma unroll
            for (int ks = 0; ks < 2; ++ks) {
                i32x4 a0 = *(const i32x4*)(ab + ks * 4096);
                i32x4 a1 = *(const i32x4*)(ab + ks * 4096 + 1024);
                i32x4 b0 = *(const i32x4*)(bb + ks * 4096);
                i32x4 b1 = *(const i32x4*)(bb + ks * 4096 + 1024);
                i32x4 b2 = *(const i32x4*)(bb + ks * 4096 + 2048);
                i32x4 b3 = *(const i32x4*)(bb + ks * 4096 + 3072);
                acc[0][0] = MFMA8(a0, b0, acc[0][0]);
                acc[0][1] = MFMA8(a0, b1, acc[0][1]);
                acc[0][2] = MFMA8(a0, b2, acc[0][2]);
                acc[0][3] = MFMA8(a0, b3, acc[0][3]);
                acc[1][0] = MFMA8(a1, b0, acc[1][0]);
                acc[1][1] = MFMA8(a1, b1, acc[1][1]);
                acc[1][2] = MFMA8(a1, b2, acc[1][2]);
                acc[1][3] = MFMA8(a1, b3, acc[1][3]);
            }
        }
        if (j + 1 < NS) {
            if (j + 2 < NS) { asm volatile("s_waitcnt vmcnt(6)" ::: "memory"); }
            else            { asm volatile("s_waitcnt vmcnt(0)" ::: "memory"); }
            __builtin_amdgcn_s_barrier();
        }
        int t = s0; s0 = s1; s1 = s2; s2 = t;
    }

    // C/D layout: col = lane&31, row = (reg&3) + 8*(reg>>2) + 4*(lane>>5)
    if (EPI == 1) {
#pragma unroll
        for (int m = 0; m < 2; ++m) {
#pragma unroll
            for (int r = 0; r < 16; ++r) {
                int v = acc[m][0][r];
                int v1 = acc[m][1][r]; v = v > v1 ? v : v1;
                int v2 = acc[m][2][r]; v = v > v2 ? v : v2;
                int v3 = acc[m][3][r]; v = v > v3 ? v : v3;
#pragma unroll
                for (int mk = 1; mk <= 16; mk <<= 1) {
                    int o = __shfl_xor(v, mk, 64);
                    v = v > o ? v : o;
                }
                if ((lane & 31) == 0) {
                    int row = by * 256 + wv * 64 + m * 32 + (r & 3) + 8 * (r >> 2) + 4 * (lane >> 5);
                    atomicMax(&rowmax[rowOff + row], v);
                }
            }
        }
#pragma unroll
        for (int m = 0; m < 2; ++m)
#pragma unroll
            for (int r = 0; r < 16; ++r) {
                int row = by * 256 + wv * 64 + m * 32 + (r & 3) + 8 * (r >> 2) + 4 * (lane >> 5);
                size_t base = (size_t)row * N + bx * 128 + (lane & 31);
#pragma unroll
                for (int n = 0; n < 4; ++n) C[base + n * 32] = acc[m][n][r];
            }
    } else {
#pragma unroll
        for (int m = 0; m < 2; ++m)
#pragma unroll
            for (int r = 0; r < 16; ++r) {
                int row = by * 256 + wv * 64 + m * 32 + (r & 3) + 8 * (r >> 2) + 4 * (lane >> 5);
                float s = os2[rowOff + row];
                size_t base = (size_t)(rowOff + row) * N + bx * 128 + (lane & 31);
#pragma unroll
                for (int n = 0; n < 4; ++n) Out[base + n * 32] = (float)acc[m][n][r] * s;
            }
    }
}

// ---------------- host ---------------------------------------------------------
extern "C" void kernel_launch(void* const* d_in, const int* in_sizes, int n_in,
                              void* d_out, int out_size, void* d_ws, size_t ws_size,
                              hipStream_t stream) {
    const float* x  = (const float*)d_in[0];
    const float* W1 = (const float*)d_in[1];
    const float* W2 = (const float*)d_in[2];
    float* out = (float*)d_out;

    const int M = 8192, K1 = 4096, H = 16384, NOUT = 4096;
    const int NPART = 2048;

    uint8_t* ws = (uint8_t*)d_ws;
    size_t off = 0;
    auto alloc = [&](size_t bytes) -> void* {
        void* p = ws + off;
        off = (off + bytes + 255) & ~(size_t)255;
        return p;
    };
    char*   wq1  = (char*)alloc((size_t)H * K1);      // blocked, KB=32
    char*   wq2  = (char*)alloc((size_t)NOUT * H);    // blocked, KB=128
    char*   xq1  = (char*)alloc((size_t)M * K1);      // blocked, KB=32
    double* pd1  = (double*)alloc(NPART * 8);
    double* pd2  = (double*)alloc(NPART * 8);
    float*  scal = (float*)alloc(256);
    float*  xs1  = (float*)alloc(M * 4);
    float*  xs2  = (float*)alloc(M * 4);
    float*  os2  = (float*)alloc(M * 4);
    float*  g1s  = (float*)alloc(M * 4);
    int*    rm1  = (int*)alloc(M * 4);

    size_t remain = (ws_size > off) ? (ws_size - off) : 0;
    size_t perRow = (size_t)H * 4 + (size_t)H;   // C1 row + xq2 row
    long Rl = (long)(remain / perRow);
    int R = (int)((Rl / 256) * 256);
    if (R > M) R = M;
    if (R < 256) R = 256;
    int*  C1  = (int*)alloc((size_t)R * H * 4);   // row-major int32, local rows
    char* xq2 = (char*)alloc((size_t)R * H);      // blocked (local rows), KB=128

    hipMemsetAsync(rm1, 0, M * 4, stream);
    k_abs_sum<<<NPART, 256, 0, stream>>>(W1, (long)H * K1 / 4, pd1);
    k_abs_sum<<<NPART, 256, 0, stream>>>(W2, (long)NOUT * H / 4, pd2);
    k_finalize<<<1, 256, 0, stream>>>(pd1, pd2, NPART, scal,
                                      1.0 / ((double)H * K1), 1.0 / ((double)NOUT * H));
    // W1: (16384/128)x(4096/128) = 128x32 = 4096 tiles; W2: 32x128 = 4096 tiles
    k_quant_w<<<4096, 256, 0, stream>>>(W1, wq1, scal, 0, 32);
    k_quant_w<<<4096, 256, 0, stream>>>(W2, wq2, scal, 1, 128);
    k_quant_x<<<M, 256, 0, stream>>>(x, xq1, xs1);

    for (int rowOff = 0; rowOff < M; rowOff += R) {
        int Mc = (M - rowOff < R) ? (M - rowOff) : R;
        int nby = Mc / 256;
        // GEMM1: [Mc x 4096] x [16384 x 4096]^T -> C1 int32 + rowmax
        k_gemm_i8<1><<<dim3(128 * nby), 256, 0, stream>>>(
            xq1 + (size_t)rowOff * K1, wq1, 32, 128, C1, rm1, nullptr, nullptr, rowOff, H);
        k_rowscale2<<<(Mc + 255) / 256, 256, 0, stream>>>(rm1, xs1, scal, xs2, os2, g1s, rowOff, Mc);
        k_quant_h<<<dim3((Mc / 128) * 128), 256, 0, stream>>>(C1, xq2, xs2, g1s, rowOff);
        // GEMM2: [Mc x 16384] x [4096 x 16384]^T -> out f32
        k_gemm_i8<2><<<dim3(32 * nby), 256, 0, stream>>>(
            xq2, wq2, 128, 32, nullptr, nullptr, out, os2, rowOff, NOUT);
    }
}